// Round 2
// baseline (471.635 us; speedup 1.0000x reference)
//
#include <hip/hip_runtime.h>
#include <hip/hip_bf16.h>
#include <stdint.h>

#define NN 4096
#define NF 128
#define NB 4

typedef __attribute__((ext_vector_type(4))) float  floatx4;
typedef __attribute__((ext_vector_type(8))) __bf16 bf16x8;

// ---------------------------------------------------------------------------
// Prep: Xpack[b][kc][n][k8] = bf16(X[b][kc*32+k8][n])   (B-fragment order)
//       wpack[kc2][n][k8]   = bf16(w[kc2*32+k8][n])
// A B-frag load (n-tile nt, k-chunk kc) is then one contiguous 1KB dwordx4.
// ---------------------------------------------------------------------------
__global__ __launch_bounds__(256) void prep_kernel(const float* __restrict__ X,
                                                   const float* __restrict__ w,
                                                   __bf16* __restrict__ Xpack,
                                                   __bf16* __restrict__ wpack) {
    const int tid = threadIdx.x;
    const int bx  = blockIdx.x;
    if (bx == 256) {  // wpack: 4 kc2 * 128 n = 512 (kc,n) pairs
        for (int p = tid; p < 512; p += 256) {
            int kc = p >> 7, n = p & 127;
#pragma unroll
            for (int k8 = 0; k8 < 32; k8 += 8) {
                bf16x8 v;
#pragma unroll
                for (int j = 0; j < 8; j++)
                    v[j] = (__bf16)w[(size_t)(kc * 32 + k8 + j) * NF + n];
                *(bf16x8*)(wpack + ((size_t)(kc * 128 + n)) * 32 + k8) = v;
            }
        }
        return;
    }
    // 256 blocks * 256 thr = 65536 = 4 b * 128 kc * 128 n ; thread -> (b,kc,n)
    int id = bx * 256 + tid;
    int b  = id >> 14;
    int kc = (id >> 7) & 127;
    int n  = id & 127;
    const float* Xp = X + ((size_t)b * NN + (size_t)kc * 32) * NF + n;  // coalesced over n
    __bf16* op = Xpack + (((size_t)b * 128 + kc) * 128 + n) * 32;       // 64B contiguous write
#pragma unroll
    for (int k8 = 0; k8 < 32; k8 += 8) {
        bf16x8 v;
#pragma unroll
        for (int j = 0; j < 8; j++)
            v[j] = (__bf16)Xp[(size_t)(k8 + j) * NF];
        *(bf16x8*)(op + k8) = v;
    }
}

// ---------------------------------------------------------------------------
// Main: block = one 16-row m-tile x 128 cols; 4 waves, wave wv owns cols
// [wv*32, wv*32+32) (2 n-tiles). 1024 blocks -> 4 blocks/CU, 16 waves/CU.
// K-loop barrier-free: A strided from global (4 waves share via L1),
// B one coalesced 1KB load per frag from Xpack. deg from the same A loads.
// ---------------------------------------------------------------------------
__global__ __launch_bounds__(256, 4) void main_kernel(const float* __restrict__ A,
                                                      const float* __restrict__ X,
                                                      const __bf16* __restrict__ Xpack,
                                                      const __bf16* __restrict__ wpack,
                                                      float* __restrict__ out) {
    __shared__ __bf16 Us[16][136];  // u = (acc+X)/deg, A-operand staging

    const int tid  = threadIdx.x;
    const int wv   = tid >> 6;
    const int lane = tid & 63;
    const int lm   = lane & 15;
    const int quad = lane >> 4;

    const int b  = blockIdx.x >> 8;        // 1024 blocks = 4 b * 256 m-tiles
    const int m0 = (blockIdx.x & 255) << 4;

    const float*  Arow = A + ((size_t)b * NN + m0 + lm) * NN + quad * 8;
    const __bf16* Bp   = Xpack + ((size_t)b * 128 * NF + (wv * 32 + lm)) * 32 + quad * 8;
    // kc stride = NF*32 = 4096 elems ; second n-tile = +16*32 = 512 elems

    floatx4 acc0 = {0.f, 0.f, 0.f, 0.f};
    floatx4 acc1 = {0.f, 0.f, 0.f, 0.f};
    float dsum = 0.f;

    floatx4 a0 = *(const floatx4*)(Arow);
    floatx4 a1 = *(const floatx4*)(Arow + 4);
    bf16x8  b0 = *(const bf16x8*)(Bp);
    bf16x8  b1 = *(const bf16x8*)(Bp + 512);

#pragma unroll 4
    for (int kc = 0; kc < 127; kc++) {
        const float*  An = Arow + (size_t)(kc + 1) * 32;
        const __bf16* Bn = Bp + (size_t)(kc + 1) * 4096;
        floatx4 na0 = *(const floatx4*)(An);
        floatx4 na1 = *(const floatx4*)(An + 4);
        bf16x8  nb0 = *(const bf16x8*)(Bn);
        bf16x8  nb1 = *(const bf16x8*)(Bn + 512);

        dsum += a0[0] + a0[1] + a0[2] + a0[3] + a1[0] + a1[1] + a1[2] + a1[3];
        bf16x8 af;
#pragma unroll
        for (int i = 0; i < 4; i++) af[i] = (__bf16)a0[i];
#pragma unroll
        for (int i = 0; i < 4; i++) af[4 + i] = (__bf16)a1[i];
        acc0 = __builtin_amdgcn_mfma_f32_16x16x32_bf16(af, b0, acc0, 0, 0, 0);
        acc1 = __builtin_amdgcn_mfma_f32_16x16x32_bf16(af, b1, acc1, 0, 0, 0);

        a0 = na0; a1 = na1; b0 = nb0; b1 = nb1;
    }
    // tail iteration (kc = 127)
    {
        dsum += a0[0] + a0[1] + a0[2] + a0[3] + a1[0] + a1[1] + a1[2] + a1[3];
        bf16x8 af;
#pragma unroll
        for (int i = 0; i < 4; i++) af[i] = (__bf16)a0[i];
#pragma unroll
        for (int i = 0; i < 4; i++) af[4 + i] = (__bf16)a1[i];
        acc0 = __builtin_amdgcn_mfma_f32_16x16x32_bf16(af, b0, acc0, 0, 0, 0);
        acc1 = __builtin_amdgcn_mfma_f32_16x16x32_bf16(af, b1, acc1, 0, 0, 0);
    }

    // deg[row lm] = full K row-sum (combine the 4 quad phases), all in-register
    dsum += __shfl_xor(dsum, 16, 64);
    dsum += __shfl_xor(dsum, 32, 64);
    float degv[4];
#pragma unroll
    for (int i = 0; i < 4; i++)
        degv[i] = __shfl(dsum, quad * 4 + i, 64) + 1.0f;  // deg for row quad*4+i

    // preload w B-frags (global, L2-hot) before the barrier
    bf16x8 wf[4][2];
#pragma unroll
    for (int kc2 = 0; kc2 < 4; kc2++)
#pragma unroll
        for (int nt = 0; nt < 2; nt++)
            wf[kc2][nt] = *(const bf16x8*)(wpack +
                ((size_t)(kc2 * 128 + wv * 32 + nt * 16 + lm)) * 32 + quad * 8);

    // u = (acc + X)/deg -> Us (bf16)
    const float* Xb = X + ((size_t)b * NN + m0) * NF;
#pragma unroll
    for (int nt = 0; nt < 2; nt++) {
        int col = wv * 32 + nt * 16 + lm;
        floatx4 accv = nt ? acc1 : acc0;
#pragma unroll
        for (int i = 0; i < 4; i++) {
            int r = quad * 4 + i;  // C-layout: row = (lane>>4)*4 + reg
            float u = (accv[i] + Xb[(size_t)r * NF + col]) / degv[i];
            Us[r][col] = (__bf16)u;
        }
    }
    __syncthreads();

    // z = u @ w  (K = 128), each wave its 2 n-tiles
    floatx4 z0 = {0.f, 0.f, 0.f, 0.f};
    floatx4 z1 = {0.f, 0.f, 0.f, 0.f};
#pragma unroll
    for (int kc2 = 0; kc2 < 4; kc2++) {
        bf16x8 ua = *(const bf16x8*)&Us[lm][kc2 * 32 + quad * 8];
        z0 = __builtin_amdgcn_mfma_f32_16x16x32_bf16(ua, wf[kc2][0], z0, 0, 0, 0);
        z1 = __builtin_amdgcn_mfma_f32_16x16x32_bf16(ua, wf[kc2][1], z1, 0, 0, 0);
    }

    // relu + store
    float* ob = out + ((size_t)b * NN + m0) * NF;
#pragma unroll
    for (int nt = 0; nt < 2; nt++) {
        int col = wv * 32 + nt * 16 + lm;
        floatx4 zv = nt ? z1 : z0;
#pragma unroll
        for (int i = 0; i < 4; i++) {
            int r = quad * 4 + i;
            float v = zv[i];
            ob[(size_t)r * NF + col] = v > 0.f ? v : 0.f;
        }
    }
}

extern "C" void kernel_launch(void* const* d_in, const int* in_sizes, int n_in,
                              void* d_out, int out_size, void* d_ws, size_t ws_size,
                              hipStream_t stream) {
    const float* A = (const float*)d_in[0];  // [4,4096,4096]
    const float* X = (const float*)d_in[1];  // [4,4096,128]
    const float* w = (const float*)d_in[2];  // [128,128]
    float* out = (float*)d_out;              // [4,4096,128]

    __bf16* Xpack = (__bf16*)d_ws;                       // 4 MB
    __bf16* wpack = Xpack + (size_t)NB * NF * NN;        // +32 KB

    prep_kernel<<<257, 256, 0, stream>>>(X, w, Xpack, wpack);
    main_kernel<<<1024, 256, 0, stream>>>(A, X, Xpack, wpack, out);
}

// Round 3
// 399.189 us; speedup vs baseline: 1.1815x; 1.1815x over previous
//
#include <hip/hip_runtime.h>
#include <hip/hip_bf16.h>
#include <stdint.h>

#define NN 4096
#define NF 128
#define NB 4
#define KC 256               // k-floats staged per stage
#define NSTAGE (NN / KC)     // 16

typedef __attribute__((ext_vector_type(4))) float  floatx4;
typedef __attribute__((ext_vector_type(8))) __bf16 bf16x8;

// async global->LDS, 16B per lane; LDS dest = uniform base + lane*16
__device__ __forceinline__ void load_lds_16(const float* g, float* l) {
    __builtin_amdgcn_global_load_lds(
        (const __attribute__((address_space(1))) uint32_t*)g,
        (__attribute__((address_space(3))) uint32_t*)l, 16, 0, 0);
}

// ---------------------------------------------------------------------------
// Prep: Xpack[b][kc][f][k8] = bf16(X[b][kc*32+k8][f])  via LDS transpose.
// Reads coalesced (X rows are 512B contiguous), writes coalesced (32B/thread).
//       wpack[kc2][n][k8]   = bf16(w[kc2*32+k8][n])
// ---------------------------------------------------------------------------
__global__ __launch_bounds__(256) void prep_kernel(const float* __restrict__ X,
                                                   const float* __restrict__ w,
                                                   __bf16* __restrict__ Xpack,
                                                   __bf16* __restrict__ wpack) {
    __shared__ float Xs[32][129];
    const int tid = threadIdx.x;
    const int bx  = blockIdx.x;
    if (bx == 512) {  // wpack: tiny
        for (int p = tid; p < 512; p += 256) {
            int kc = p >> 7, n = p & 127;
#pragma unroll
            for (int k8 = 0; k8 < 32; k8 += 8) {
                bf16x8 v;
#pragma unroll
                for (int j = 0; j < 8; j++)
                    v[j] = (__bf16)w[(size_t)(kc * 32 + k8 + j) * NF + n];
                *(bf16x8*)(wpack + ((size_t)(kc * 128 + n)) * 32 + k8) = v;
            }
        }
        return;
    }
    // 512 blocks = 4 b * 128 kc ; tile = X[b][kc*32 .. +32][0..128]
    const int b  = bx >> 7;
    const int kc = bx & 127;
    const float* Xt = X + ((size_t)b * NN + (size_t)kc * 32) * NF;
#pragma unroll
    for (int j = 0; j < 16; j++) {
        int i = tid + j * 256;           // 4096 = 32k x 128f, coalesced
        Xs[i >> 7][i & 127] = Xt[i];
    }
    __syncthreads();
    const int f  = tid >> 1;
    const int kh = (tid & 1) * 16;
    bf16x8 v0, v1;
#pragma unroll
    for (int j = 0; j < 8; j++) v0[j] = (__bf16)Xs[kh + j][f];
#pragma unroll
    for (int j = 0; j < 8; j++) v1[j] = (__bf16)Xs[kh + 8 + j][f];
    __bf16* op = Xpack + (((size_t)b * 128 + kc) * 128 + f) * 32 + kh;
    *(bf16x8*)op = v0;
    *(bf16x8*)(op + 8) = v1;
}

// ---------------------------------------------------------------------------
// Main: block = 16 rows x 128 cols; 4 waves, wave wv owns cols [wv*32,+32).
// A staged fp32 -> LDS via global_load_lds (coalesced 1KB rows, double buf),
// fragments via ds_read_b128 + cvt; B frags 1KB contiguous from L2-hot Xpack.
// 1024 blocks -> 4 blocks/CU (LDS 37.6KB), 16 waves/CU.
// ---------------------------------------------------------------------------
__global__ __launch_bounds__(256, 4) void main_kernel(const float* __restrict__ A,
                                                      const float* __restrict__ X,
                                                      const __bf16* __restrict__ Xpack,
                                                      const __bf16* __restrict__ wpack,
                                                      float* __restrict__ out) {
    __shared__ float  At[2][16][260];  // row-padded; DMA writes [0..256) per row
    __shared__ __bf16 Us[16][136];

    const int tid  = threadIdx.x;
    const int wv   = tid >> 6;
    const int lane = tid & 63;
    const int lm   = lane & 15;
    const int quad = lane >> 4;

    const int b  = blockIdx.x >> 8;        // 1024 blocks = 4 b * 256 m-tiles
    const int m0 = (blockIdx.x & 255) << 4;

    // per-wave DMA source rows (wave wv stages rows wv*4 .. wv*4+3)
    const float* Ag[4];
#pragma unroll
    for (int j = 0; j < 4; j++)
        Ag[j] = A + ((size_t)b * NN + m0 + wv * 4 + j) * NN + lane * 4;

    const __bf16* Bbase = Xpack + ((size_t)b * 128 * NF + (wv * 32 + lm)) * 32 + quad * 8;

    floatx4 acc0 = {0.f, 0.f, 0.f, 0.f};
    floatx4 acc1 = {0.f, 0.f, 0.f, 0.f};
    float dsum = 0.f;

    // stage 0 into buf 0
#pragma unroll
    for (int j = 0; j < 4; j++)
        load_lds_16(Ag[j], &At[0][wv * 4 + j][0]);

    for (int s = 0; s < NSTAGE; s++) {
        const int buf = s & 1;
        __builtin_amdgcn_s_waitcnt(0x0f70);  // vmcnt(0): my 4 DMA done
        __syncthreads();                     // tile visible to all; prev reads done
        if (s + 1 < NSTAGE) {
#pragma unroll
            for (int j = 0; j < 4; j++)
                load_lds_16(Ag[j] + (size_t)(s + 1) * KC, &At[buf ^ 1][wv * 4 + j][0]);
        }
        const __bf16* Bs = Bbase + (size_t)s * 8 * 4096;
#pragma unroll
        for (int kk = 0; kk < 8; kk++) {
            bf16x8 b0 = *(const bf16x8*)(Bs + (size_t)kk * 4096);
            bf16x8 b1 = *(const bf16x8*)(Bs + (size_t)kk * 4096 + 512);
            floatx4 a0 = *(const floatx4*)&At[buf][lm][kk * 32 + quad * 8];
            floatx4 a1 = *(const floatx4*)&At[buf][lm][kk * 32 + quad * 8 + 4];
            dsum += a0[0] + a0[1] + a0[2] + a0[3] + a1[0] + a1[1] + a1[2] + a1[3];
            bf16x8 af;
#pragma unroll
            for (int i = 0; i < 4; i++) af[i] = (__bf16)a0[i];
#pragma unroll
            for (int i = 0; i < 4; i++) af[4 + i] = (__bf16)a1[i];
            acc0 = __builtin_amdgcn_mfma_f32_16x16x32_bf16(af, b0, acc0, 0, 0, 0);
            acc1 = __builtin_amdgcn_mfma_f32_16x16x32_bf16(af, b1, acc1, 0, 0, 0);
        }
    }

    // deg[row lm]: combine the 4 quad k-phases (each wave has the full sum)
    dsum += __shfl_xor(dsum, 16, 64);
    dsum += __shfl_xor(dsum, 32, 64);
    float degv[4];
#pragma unroll
    for (int i = 0; i < 4; i++)
        degv[i] = __shfl(dsum, quad * 4 + i, 64) + 1.0f;  // deg for row quad*4+i

    // preload w B-frags
    bf16x8 wf[4][2];
#pragma unroll
    for (int kc2 = 0; kc2 < 4; kc2++)
#pragma unroll
        for (int nt = 0; nt < 2; nt++)
            wf[kc2][nt] = *(const bf16x8*)(wpack +
                ((size_t)(kc2 * 128 + wv * 32 + nt * 16 + lm)) * 32 + quad * 8);

    // u = (acc + X)/deg -> Us (bf16)
    const float* Xb = X + ((size_t)b * NN + m0) * NF;
#pragma unroll
    for (int nt = 0; nt < 2; nt++) {
        int col = wv * 32 + nt * 16 + lm;
        floatx4 accv = nt ? acc1 : acc0;
#pragma unroll
        for (int i = 0; i < 4; i++) {
            int r = quad * 4 + i;  // C-layout: row = (lane>>4)*4 + reg
            float u = (accv[i] + Xb[(size_t)r * NF + col]) / degv[i];
            Us[r][col] = (__bf16)u;
        }
    }
    __syncthreads();

    // z = u @ w  (K = 128)
    floatx4 z0 = {0.f, 0.f, 0.f, 0.f};
    floatx4 z1 = {0.f, 0.f, 0.f, 0.f};
#pragma unroll
    for (int kc2 = 0; kc2 < 4; kc2++) {
        bf16x8 ua = *(const bf16x8*)&Us[lm][kc2 * 32 + quad * 8];
        z0 = __builtin_amdgcn_mfma_f32_16x16x32_bf16(ua, wf[kc2][0], z0, 0, 0, 0);
        z1 = __builtin_amdgcn_mfma_f32_16x16x32_bf16(ua, wf[kc2][1], z1, 0, 0, 0);
    }

    // relu + store
    float* ob = out + ((size_t)b * NN + m0) * NF;
#pragma unroll
    for (int nt = 0; nt < 2; nt++) {
        int col = wv * 32 + nt * 16 + lm;
        floatx4 zv = nt ? z1 : z0;
#pragma unroll
        for (int i = 0; i < 4; i++) {
            int r = quad * 4 + i;
            float v = zv[i];
            ob[(size_t)r * NF + col] = v > 0.f ? v : 0.f;
        }
    }
}

extern "C" void kernel_launch(void* const* d_in, const int* in_sizes, int n_in,
                              void* d_out, int out_size, void* d_ws, size_t ws_size,
                              hipStream_t stream) {
    const float* A = (const float*)d_in[0];  // [4,4096,4096]
    const float* X = (const float*)d_in[1];  // [4,4096,128]
    const float* w = (const float*)d_in[2];  // [128,128]
    float* out = (float*)d_out;              // [4,4096,128]

    __bf16* Xpack = (__bf16*)d_ws;                 // 4 MB
    __bf16* wpack = Xpack + (size_t)NB * NF * NN;  // +32 KB

    prep_kernel<<<513, 256, 0, stream>>>(X, w, Xpack, wpack);
    main_kernel<<<1024, 256, 0, stream>>>(A, X, Xpack, wpack, out);
}

// Round 4
// 390.059 us; speedup vs baseline: 1.2091x; 1.0234x over previous
//
#include <hip/hip_runtime.h>
#include <hip/hip_bf16.h>
#include <stdint.h>

#define NN 4096
#define NF 128
#define NB 4
#define KC 128               // k-floats staged per stage
#define NSTAGE (NN / KC)     // 32

typedef __attribute__((ext_vector_type(4))) float  floatx4;
typedef __attribute__((ext_vector_type(8))) __bf16 bf16x8;

// async global->LDS, 16B per lane; LDS dest = uniform base + lane*16
__device__ __forceinline__ void load_lds_16(const float* g, float* l) {
    __builtin_amdgcn_global_load_lds(
        (const __attribute__((address_space(1))) uint32_t*)g,
        (__attribute__((address_space(3))) uint32_t*)l, 16, 0, 0);
}

// ---------------------------------------------------------------------------
// Prep: Xpack[b][kc][f][k8] = bf16(X[b][kc*32+k8][f])  via LDS transpose.
//       wpack[kc2][n][k8]   = bf16(w[kc2*32+k8][n])
// ---------------------------------------------------------------------------
__global__ __launch_bounds__(256) void prep_kernel(const float* __restrict__ X,
                                                   const float* __restrict__ w,
                                                   __bf16* __restrict__ Xpack,
                                                   __bf16* __restrict__ wpack) {
    __shared__ float Xs[32][129];
    const int tid = threadIdx.x;
    const int bx  = blockIdx.x;
    if (bx == 512) {  // wpack: tiny
        for (int p = tid; p < 512; p += 256) {
            int kc = p >> 7, n = p & 127;
#pragma unroll
            for (int k8 = 0; k8 < 32; k8 += 8) {
                bf16x8 v;
#pragma unroll
                for (int j = 0; j < 8; j++)
                    v[j] = (__bf16)w[(size_t)(kc * 32 + k8 + j) * NF + n];
                *(bf16x8*)(wpack + ((size_t)(kc * 128 + n)) * 32 + k8) = v;
            }
        }
        return;
    }
    // 512 blocks = 4 b * 128 kc ; tile = X[b][kc*32 .. +32][0..128]
    const int b  = bx >> 7;
    const int kc = bx & 127;
    const float* Xt = X + ((size_t)b * NN + (size_t)kc * 32) * NF;
#pragma unroll
    for (int j = 0; j < 16; j++) {
        int i = tid + j * 256;           // coalesced
        Xs[i >> 7][i & 127] = Xt[i];
    }
    __syncthreads();
    const int f  = tid >> 1;
    const int kh = (tid & 1) * 16;
    bf16x8 v0, v1;
#pragma unroll
    for (int j = 0; j < 8; j++) v0[j] = (__bf16)Xs[kh + j][f];
#pragma unroll
    for (int j = 0; j < 8; j++) v1[j] = (__bf16)Xs[kh + 8 + j][f];
    __bf16* op = Xpack + (((size_t)b * 128 + kc) * 128 + f) * 32 + kh;
    *(bf16x8*)op = v0;
    *(bf16x8*)(op + 8) = v1;
}

// ---------------------------------------------------------------------------
// Main: block = 64 rows x 128 cols (256 blocks -> 1/CU, 8 waves).
// Wave (rg,cg): rows [rg*32,+32) (2 subtiles), cols [cg*32,+32) (2 n-frags).
// A fp32 -> LDS via global_load_lds: 1KB chunks = 2 rows x 512B, chunk-padded
// layout At[32][260] (16B pad per chunk keeps DMA contiguity, breaks bank
// aliasing for ds_read_b128 frag reads). B-frags: contiguous 1KB loads from
// L2/LLC-hot Xpack, reused across 2 m-subtiles (B traffic 1GB -> 256MB).
// ---------------------------------------------------------------------------
__global__ __launch_bounds__(512, 2) void main_kernel(const float* __restrict__ A,
                                                      const float* __restrict__ X,
                                                      const __bf16* __restrict__ Xpack,
                                                      const __bf16* __restrict__ wpack,
                                                      float* __restrict__ out) {
    __shared__ float  At[2][32][260];  // chunk g = rows 2g,2g+1 of stage tile
    __shared__ __bf16 Us[64][136];

    const int tid  = threadIdx.x;
    const int wv   = tid >> 6;
    const int lane = tid & 63;
    const int lm   = lane & 15;
    const int quad = lane >> 4;
    const int rg   = wv & 1;
    const int cg   = wv >> 1;

    const int b  = blockIdx.x >> 6;        // 256 blocks = 4 b * 64 m-tiles
    const int m0 = (blockIdx.x & 63) << 6;

    // DMA source: wave stages chunks g = wv*4..+3 ; chunk g = rows 2g, 2g+1.
    // lanes 0-31 -> row 2g, lanes 32-63 -> row 2g+1 (2 coalesced 512B segs).
    const float* Asrc = A + ((size_t)b * NN + m0 + (lane >> 5)) * NN + (lane & 31) * 4;

    const __bf16* Bbase = Xpack + ((size_t)b * 128 * NF + (cg * 32 + lm)) * 32 + quad * 8;

    floatx4 acc[2][2];
#pragma unroll
    for (int i = 0; i < 2; i++)
#pragma unroll
        for (int j = 0; j < 2; j++) acc[i][j] = (floatx4){0.f, 0.f, 0.f, 0.f};
    float ds0 = 0.f, ds1 = 0.f;

    // prologue: stage 0 -> buf 0
#pragma unroll
    for (int j = 0; j < 4; j++)
        load_lds_16(Asrc + (size_t)(wv * 4 + j) * 2 * NN, &At[0][wv * 4 + j][0]);

    const int r0 = rg * 32 + lm;
    const int r1 = r0 + 16;
    const int ofs0 = (r0 & 1) * 128 + quad * 8;
    const int ofs1 = (r1 & 1) * 128 + quad * 8;

    for (int s = 0; s < NSTAGE; s++) {
        const int buf = s & 1;
        __builtin_amdgcn_s_waitcnt(0x0f70);  // vmcnt(0): my DMA done
        __syncthreads();
        if (s + 1 < NSTAGE) {
#pragma unroll
            for (int j = 0; j < 4; j++)
                load_lds_16(Asrc + (size_t)(wv * 4 + j) * 2 * NN + (size_t)(s + 1) * KC,
                            &At[buf ^ 1][wv * 4 + j][0]);
        }
        const float(*Ab)[260] = At[buf];
        const __bf16* Bs = Bbase + (size_t)s * 4 * 4096;
#pragma unroll
        for (int kk = 0; kk < 4; kk++) {
            bf16x8 b0 = *(const bf16x8*)(Bs + (size_t)kk * 4096);
            bf16x8 b1 = *(const bf16x8*)(Bs + (size_t)kk * 4096 + 512);
            floatx4 a00 = *(const floatx4*)&Ab[r0 >> 1][ofs0 + kk * 32];
            floatx4 a01 = *(const floatx4*)&Ab[r0 >> 1][ofs0 + kk * 32 + 4];
            floatx4 a10 = *(const floatx4*)&Ab[r1 >> 1][ofs1 + kk * 32];
            floatx4 a11 = *(const floatx4*)&Ab[r1 >> 1][ofs1 + kk * 32 + 4];
            ds0 += a00[0] + a00[1] + a00[2] + a00[3] + a01[0] + a01[1] + a01[2] + a01[3];
            ds1 += a10[0] + a10[1] + a10[2] + a10[3] + a11[0] + a11[1] + a11[2] + a11[3];
            bf16x8 af0, af1;
#pragma unroll
            for (int i = 0; i < 4; i++) { af0[i] = (__bf16)a00[i]; af0[4 + i] = (__bf16)a01[i]; }
#pragma unroll
            for (int i = 0; i < 4; i++) { af1[i] = (__bf16)a10[i]; af1[4 + i] = (__bf16)a11[i]; }
            acc[0][0] = __builtin_amdgcn_mfma_f32_16x16x32_bf16(af0, b0, acc[0][0], 0, 0, 0);
            acc[0][1] = __builtin_amdgcn_mfma_f32_16x16x32_bf16(af0, b1, acc[0][1], 0, 0, 0);
            acc[1][0] = __builtin_amdgcn_mfma_f32_16x16x32_bf16(af1, b0, acc[1][0], 0, 0, 0);
            acc[1][1] = __builtin_amdgcn_mfma_f32_16x16x32_bf16(af1, b1, acc[1][1], 0, 0, 0);
        }
    }

    // full row-sums: combine the 4 quad k-phases
    ds0 += __shfl_xor(ds0, 16, 64); ds0 += __shfl_xor(ds0, 32, 64);
    ds1 += __shfl_xor(ds1, 16, 64); ds1 += __shfl_xor(ds1, 32, 64);
    float deg0[4], deg1[4];
#pragma unroll
    for (int i = 0; i < 4; i++) {
        deg0[i] = __shfl(ds0, quad * 4 + i, 64) + 1.0f;  // row rg*32 + quad*4+i
        deg1[i] = __shfl(ds1, quad * 4 + i, 64) + 1.0f;  // row rg*32+16 + quad*4+i
    }

    // preload w B-frags (L2-hot)
    bf16x8 wf[4][2];
#pragma unroll
    for (int kc2 = 0; kc2 < 4; kc2++)
#pragma unroll
        for (int nt = 0; nt < 2; nt++)
            wf[kc2][nt] = *(const bf16x8*)(wpack +
                ((size_t)(kc2 * 128 + cg * 32 + nt * 16 + lm)) * 32 + quad * 8);

    // u = (acc + X)/deg -> Us (bf16)
    const float* Xb = X + ((size_t)b * NN + m0) * NF;
#pragma unroll
    for (int sub = 0; sub < 2; sub++) {
#pragma unroll
        for (int nt = 0; nt < 2; nt++) {
            int col = cg * 32 + nt * 16 + lm;
#pragma unroll
            for (int i = 0; i < 4; i++) {
                int r = rg * 32 + sub * 16 + quad * 4 + i;  // C-layout row
                float d = sub ? deg1[i] : deg0[i];
                float u = (acc[sub][nt][i] + Xb[(size_t)r * NF + col]) / d;
                Us[r][col] = (__bf16)u;
            }
        }
    }
    __syncthreads();

    // z = u @ w (K=128); wave handles its rows (2 subtiles) x its 32 cols
    float* ob = out + ((size_t)b * NN + m0) * NF;
#pragma unroll
    for (int sub = 0; sub < 2; sub++) {
        int rm = rg * 32 + sub * 16;
        floatx4 z0 = {0.f, 0.f, 0.f, 0.f};
        floatx4 z1 = {0.f, 0.f, 0.f, 0.f};
#pragma unroll
        for (int kc2 = 0; kc2 < 4; kc2++) {
            bf16x8 ua = *(const bf16x8*)&Us[rm + lm][kc2 * 32 + quad * 8];
            z0 = __builtin_amdgcn_mfma_f32_16x16x32_bf16(ua, wf[kc2][0], z0, 0, 0, 0);
            z1 = __builtin_amdgcn_mfma_f32_16x16x32_bf16(ua, wf[kc2][1], z1, 0, 0, 0);
        }
#pragma unroll
        for (int nt = 0; nt < 2; nt++) {
            int col = cg * 32 + nt * 16 + lm;
            floatx4 zv = nt ? z1 : z0;
#pragma unroll
            for (int i = 0; i < 4; i++) {
                int r = rm + quad * 4 + i;
                float v = zv[i];
                ob[(size_t)r * NF + col] = v > 0.f ? v : 0.f;
            }
        }
    }
}

extern "C" void kernel_launch(void* const* d_in, const int* in_sizes, int n_in,
                              void* d_out, int out_size, void* d_ws, size_t ws_size,
                              hipStream_t stream) {
    const float* A = (const float*)d_in[0];  // [4,4096,4096]
    const float* X = (const float*)d_in[1];  // [4,4096,128]
    const float* w = (const float*)d_in[2];  // [128,128]
    float* out = (float*)d_out;              // [4,4096,128]

    __bf16* Xpack = (__bf16*)d_ws;                 // 4 MB
    __bf16* wpack = Xpack + (size_t)NB * NF * NN;  // +32 KB

    prep_kernel<<<513, 256, 0, stream>>>(X, w, Xpack, wpack);
    main_kernel<<<256, 512, 0, stream>>>(A, X, Xpack, wpack, out);
}